// Round 20
// baseline (241.647 us; speedup 1.0000x reference)
//
#include <hip/hip_runtime.h>
#include <hip/hip_bf16.h>

typedef __attribute__((ext_vector_type(8))) __bf16 bf16x8;
typedef __attribute__((ext_vector_type(4))) float f32x4;

#define BATCH 16
#define LSEQ 2048
#define DIM 128
#define EPITCH 2056
#define NKBLK 64   // 2048 / 32

__device__ __forceinline__ bf16x8 cvt8(float4 a, float4 b) {
    bf16x8 r;
    r[0] = (__bf16)a.x; r[1] = (__bf16)a.y; r[2] = (__bf16)a.z; r[3] = (__bf16)a.w;
    r[4] = (__bf16)b.x; r[5] = (__bf16)b.y; r[6] = (__bf16)b.z; r[7] = (__bf16)b.w;
    return r;
}

// ============ preproc: K -> fragment-blocked Kf[b][kblk][j][lane] ============
__global__ __launch_bounds__(256)
void pack_k_kernel(const float* __restrict__ kg, bf16x8* __restrict__ kf) {
    __shared__ __bf16 Ks[32][DIM + 8];
    const int kblk = blockIdx.x, b = blockIdx.y;
    const int tid = threadIdx.x;
    {
        const int r = tid >> 3, c4 = tid & 7;
        const float* src = kg + ((size_t)b * LSEQ + kblk * 32 + r) * DIM;
        #pragma unroll
        for (int jj = 0; jj < 4; ++jj) {
            const int c = (c4 + 8 * jj) * 4;
            float4 x = *reinterpret_cast<const float4*>(src + c);
            Ks[r][c + 0] = (__bf16)x.x; Ks[r][c + 1] = (__bf16)x.y;
            Ks[r][c + 2] = (__bf16)x.z; Ks[r][c + 3] = (__bf16)x.w;
        }
    }
    __syncthreads();
    const int lane = tid & 63, w = tid >> 6;
    const int g = lane >> 4, li = lane & 15;
    bf16x8* dst = kf + ((size_t)b * NKBLK + kblk) * 8 * 64;
    #pragma unroll
    for (int jj = 0; jj < 2; ++jj) {
        const int j = 2 * w + jj;
        const int t = j >> 2, d = j & 3;
        bf16x8 v;
        #pragma unroll
        for (int e = 0; e < 8; ++e) v[e] = Ks[t * 16 + li][d * 32 + g * 8 + e];
        dst[j * 64 + lane] = v;
    }
}

// ============ preproc: V -> fragment-blocked Vf[b][kblk][dt][lane] ============
__global__ __launch_bounds__(256)
void pack_v_kernel(const float* __restrict__ vg, bf16x8* __restrict__ vf) {
    __shared__ __bf16 Vs[32][DIM + 8];
    const int kblk = blockIdx.x, b = blockIdx.y;
    const int tid = threadIdx.x;
    {
        const int r = tid >> 3, c4 = tid & 7;
        const float* src = vg + ((size_t)b * LSEQ + kblk * 32 + r) * DIM;
        #pragma unroll
        for (int jj = 0; jj < 4; ++jj) {
            const int c = (c4 + 8 * jj) * 4;
            float4 x = *reinterpret_cast<const float4*>(src + c);
            Vs[r][c + 0] = (__bf16)x.x; Vs[r][c + 1] = (__bf16)x.y;
            Vs[r][c + 2] = (__bf16)x.z; Vs[r][c + 3] = (__bf16)x.w;
        }
    }
    __syncthreads();
    const int lane = tid & 63, w = tid >> 6;
    const int g = lane >> 4, li = lane & 15;
    bf16x8* dst = vf + ((size_t)b * NKBLK + kblk) * 8 * 64;
    #pragma unroll
    for (int jj = 0; jj < 2; ++jj) {
        const int dt = 2 * w + jj;
        bf16x8 v;
        #pragma unroll
        for (int e = 0; e < 8; ++e) v[e] = Vs[g * 8 + e][dt * 16 + li];
        dst[dt * 64 + lane] = v;
    }
}

// ==== attn_fused: 8 waves = 4 q-tiles x 2 K-halves; intra-block K-split; 2-pass ====
__global__ __launch_bounds__(512, 4)
void attn_fused(const float* __restrict__ qg,
                const bf16x8* __restrict__ kf,
                const bf16x8* __restrict__ vf,
                const int* __restrict__ maskg,
                float* __restrict__ og,
                float* __restrict__ wg)
{
    __shared__ bf16x8 Kst[2][512];                     // 16 KB (per-half dbuf-free staging)
    __shared__ __align__(16) __bf16 P[8][16][40];      // 10.2 KB
    __shared__ unsigned char MB[4][NKBLK][64];         // 16 KB  (qt x kblk x lane)
    __shared__ __align__(16) float U[64 * DIM];        // 32 KB: Osum (boundary) / Wst (pass 2)
    __shared__ float rowpart[2][64];
    __shared__ float rinvS[64];

    const int tid  = threadIdx.x;
    const int wave = tid >> 6;      // 0..7
    const int lane = tid & 63;
    const int g    = lane >> 4;
    const int li   = lane & 15;
    const int qt   = wave & 3;      // q-tile within block
    const int kh   = wave >> 2;     // K half (0/1)
    const int gtid = tid & 255;     // id within kh group (256 threads)

    // XCD pinning: batch b -> xcd b%8
    const int wgid = blockIdx.x;           // 0..511
    const int xcd  = wgid & 7;
    const int rest = wgid >> 3;            // 0..63
    const int b    = xcd + 8 * (rest & 1);
    const int qb   = rest >> 1;            // 0..31 (64-query block)
    const int q0   = qb * 64 + qt * 16;    // this wave's 16 queries
    const int kbase = kh * 32;             // this wave's kblk range

    const size_t bb = (size_t)b * LSEQ;

    // zero the O-combine region (U used as Osum at the pass boundary)
    for (int i = tid; i < 64 * DIM; i += 512) U[i] = 0.0f;

    // Q fragments with scale*log2(e)
    const float qscale = 0.08838834764831845f * 1.4426950408889634f;
    bf16x8 qf[4];
    {
        const float* qrow = qg + (bb + q0 + li) * DIM + g * 8;
        #pragma unroll
        for (int d = 0; d < 4; ++d) {
            const float4* p4 = reinterpret_cast<const float4*>(qrow + d * 32);
            float4 x = p4[0];
            float4 y = p4[1];
            x.x *= qscale; x.y *= qscale; x.z *= qscale; x.w *= qscale;
            y.x *= qscale; y.y *= qscale; y.z *= qscale; y.w *= qscale;
            qf[d] = cvt8(x, y);
        }
    }

    float rsum[4] = {0.f, 0.f, 0.f, 0.f};
    f32x4 accO[8];
    #pragma unroll
    for (int i = 0; i < 8; ++i) accO[i] = (f32x4){0.f, 0.f, 0.f, 0.f};

    const bf16x8* KbU = kf + (size_t)b * NKBLK * 512;
    const bf16x8* VbL = vf + (size_t)b * NKBLK * 512 + lane;
    // mask in fragment order: element (t2,r) at kblk = mpQ[r*LSEQ + kblk*32 + t2*16]
    const int* mpQ = maskg + (bb + q0 + g * 4) * (size_t)LSEQ + li;

    // ================= PASS 1: partial rowsum + PV =================
    bf16x8 ka  = KbU[(size_t)kbase * 512 + gtid];
    bf16x8 kb2 = KbU[(size_t)kbase * 512 + 256 + gtid];
    int mcur[8], mnxt[8];
    #pragma unroll
    for (int j = 0; j < 8; ++j) {
        const int t2 = j >> 2, r = j & 3;
        mcur[j] = mpQ[(size_t)r * LSEQ + kbase * 32 + t2 * 16];
    }

    for (int it = 0; it < 32; ++it) {
        const int kblk = kbase + it;
        Kst[kh][gtid] = ka; Kst[kh][256 + gtid] = kb2;
        __syncthreads();

        bf16x8 kc[8];
        #pragma unroll
        for (int j = 0; j < 8; ++j) kc[j] = Kst[kh][j * 64 + lane];

        bf16x8 vc[8];
        #pragma unroll
        for (int dt = 0; dt < 8; ++dt) vc[dt] = VbL[(size_t)kblk * 512 + dt * 64];

        if (it + 1 < 32) {
            const size_t un = (size_t)(kblk + 1) * 512;
            ka = KbU[un + gtid];  kb2 = KbU[un + 256 + gtid];
            #pragma unroll
            for (int j = 0; j < 8; ++j) {
                const int t2 = j >> 2, r = j & 3;
                mnxt[j] = mpQ[(size_t)r * LSEQ + (kblk + 1) * 32 + t2 * 16];
            }
        }
        __syncthreads();

        // QK^T
        f32x4 s0 = (f32x4){0.f, 0.f, 0.f, 0.f};
        f32x4 s1 = (f32x4){0.f, 0.f, 0.f, 0.f};
        #pragma unroll
        for (int d = 0; d < 4; ++d) {
            s0 = __builtin_amdgcn_mfma_f32_16x16x32_bf16(qf[d], kc[d],     s0, 0, 0, 0);
            s1 = __builtin_amdgcn_mfma_f32_16x16x32_bf16(qf[d], kc[4 + d], s1, 0, 0, 0);
        }

        // mask + exp2 + P stage + rowsum; pack byte for pass 2
        unsigned byte = 0;
        #pragma unroll
        for (int t2 = 0; t2 < 2; ++t2) {
            f32x4 sv = t2 ? s1 : s0;
            #pragma unroll
            for (int r = 0; r < 4; ++r) {
                const int j = t2 * 4 + r;
                const bool msk = (mcur[j] != 0);
                byte |= (msk ? 1u : 0u) << j;
                float sc = msk ? -1.0e9f : sv[r];
                float ev = __builtin_amdgcn_exp2f(sc);
                rsum[r] += ev;
                P[wave][g * 4 + r][t2 * 16 + li] = (__bf16)ev;
            }
        }
        MB[qt][kblk][lane] = (unsigned char)byte;

        // PV
        {
            bf16x8 af = *reinterpret_cast<const bf16x8*>(&P[wave][li][g * 8]);
            #pragma unroll
            for (int dt = 0; dt < 8; ++dt)
                accO[dt] = __builtin_amdgcn_mfma_f32_16x16x32_bf16(af, vc[dt], accO[dt], 0, 0, 0);
        }

        #pragma unroll
        for (int j = 0; j < 8; ++j) mcur[j] = mnxt[j];
    }

    // intra-wave partial rowsum reduce across li lanes
    #pragma unroll
    for (int off = 1; off < 16; off <<= 1) {
        #pragma unroll
        for (int r = 0; r < 4; ++r) rsum[r] += __shfl_xor(rsum[r], off, 64);
    }
    if (li == 0) {
        #pragma unroll
        for (int r = 0; r < 4; ++r) rowpart[kh][qt * 16 + g * 4 + r] = rsum[r];
    }
    __syncthreads();   // zero-init + rowpart + all pass-1 work complete

    // combine O partials across the 2 K-halves (LDS atomics into U)
    #pragma unroll
    for (int dt = 0; dt < 8; ++dt)
        #pragma unroll
        for (int r = 0; r < 4; ++r)
            atomicAdd(&U[(qt * 16 + g * 4 + r) * DIM + dt * 16 + li], accO[dt][r]);
    if (tid < 64)
        rinvS[tid] = 1.0f / (rowpart[0][tid] + rowpart[1][tid]);
    __syncthreads();   // U complete, rinvS complete

    float rinv[4];
    #pragma unroll
    for (int r = 0; r < 4; ++r) rinv[r] = rinvS[qt * 16 + g * 4 + r];

    // O write: coalesced f32x4 nt (64 rows x 128)
    {
        float* ob = og + (bb + qb * 64) * DIM;
        const f32x4* os4 = reinterpret_cast<const f32x4*>(U);
        #pragma unroll
        for (int u = 0; u < 4; ++u) {
            const int i4 = u * 512 + tid;          // 2048 units
            const int row = i4 >> 5;
            f32x4 x = os4[i4];
            const float inv = rinvS[row];
            x[0] *= inv; x[1] *= inv; x[2] *= inv; x[3] *= inv;
            __builtin_nontemporal_store(x, reinterpret_cast<f32x4*>(ob + i4 * 4));
        }
    }
    __syncthreads();   // all U reads done; safe to reuse U as Wst

    // ================= PASS 2: recompute QK^T over this wave's half; write W =================
    typedef float WstRow[16][36];
    WstRow* Wst = reinterpret_cast<WstRow*>(U);        // Wst[8][16][36] = 18.4 KB <= 32 KB

    ka  = KbU[(size_t)kbase * 512 + gtid];
    kb2 = KbU[(size_t)kbase * 512 + 256 + gtid];
    float* wrow = wg + (bb + q0) * (size_t)LSEQ;

    for (int it = 0; it < 32; ++it) {
        const int kblk = kbase + it;
        Kst[kh][gtid] = ka; Kst[kh][256 + gtid] = kb2;
        __syncthreads();

        bf16x8 kc[8];
        #pragma unroll
        for (int j = 0; j < 8; ++j) kc[j] = Kst[kh][j * 64 + lane];
        const unsigned byte = MB[qt][kblk][lane];

        if (it + 1 < 32) {
            const size_t un = (size_t)(kblk + 1) * 512;
            ka = KbU[un + gtid];  kb2 = KbU[un + 256 + gtid];
        }
        __syncthreads();

        f32x4 s0 = (f32x4){0.f, 0.f, 0.f, 0.f};
        f32x4 s1 = (f32x4){0.f, 0.f, 0.f, 0.f};
        #pragma unroll
        for (int d = 0; d < 4; ++d) {
            s0 = __builtin_amdgcn_mfma_f32_16x16x32_bf16(qf[d], kc[d],     s0, 0, 0, 0);
            s1 = __builtin_amdgcn_mfma_f32_16x16x32_bf16(qf[d], kc[4 + d], s1, 0, 0, 0);
        }

        // stage W tile in LDS (per-wave region, same-wave in-order)
        #pragma unroll
        for (int t2 = 0; t2 < 2; ++t2) {
            f32x4 sv = t2 ? s1 : s0;
            #pragma unroll
            for (int r = 0; r < 4; ++r) {
                float sc = ((byte >> (t2 * 4 + r)) & 1u) ? -1.0e9f : sv[r];
                Wst[wave][g * 4 + r][t2 * 16 + li] =
                    __builtin_amdgcn_exp2f(sc) * rinv[r];
            }
        }

        // full-line W write: 8 lanes x 16B = one contiguous 128B line per row
        #pragma unroll
        for (int pp = 0; pp < 2; ++pp) {
            const int row = pp * 8 + (lane >> 3);
            const int col = (lane & 7) * 4;
            f32x4 wv = *reinterpret_cast<const f32x4*>(&Wst[wave][row][col]);
            __builtin_nontemporal_store(wv,
                reinterpret_cast<f32x4*>(wrow + (size_t)row * LSEQ + kblk * 32 + col));
        }
    }
}

// ========================= fallback (no workspace) =========================
__global__ __launch_bounds__(256, 2)
void sdpa_fused_plain(const float* __restrict__ qg,
                      const float* __restrict__ kg,
                      const float* __restrict__ vg,
                      const int*   __restrict__ maskg,
                      float* __restrict__ og,
                      float* __restrict__ wg)
{
    __shared__ __align__(16) __bf16 Es[16 * EPITCH];
    __shared__ float Osum[16 * DIM];
    __shared__ float rowpart[4][16];
    __shared__ float rowinv[16];

    const int tid  = threadIdx.x;
    const int wave = tid >> 6;
    const int lane = tid & 63;
    const int g    = lane >> 4;
    const int li   = lane & 15;
    const int qt = blockIdx.x;
    const int b  = blockIdx.y;
    const int q0 = qt * 16;

    for (int i = tid; i < 16 * DIM; i += 256) Osum[i] = 0.0f;

    const float qscale = 0.08838834764831845f * 1.4426950408889634f;
    bf16x8 qf[4];
    {
        const float* qrow = qg + ((size_t)b * LSEQ + q0 + li) * DIM + g * 8;
        #pragma unroll
        for (int d = 0; d < 4; ++d) {
            const float4* p4 = reinterpret_cast<const float4*>(qrow + d * 32);
            float4 x = p4[0];
            float4 y = p4[1];
            x.x *= qscale; x.y *= qscale; x.z *= qscale; x.w *= qscale;
            y.x *= qscale; y.y *= qscale; y.z *= qscale; y.w *= qscale;
            qf[d] = cvt8(x, y);
        }
    }

    float rsum[4] = {0.f, 0.f, 0.f, 0.f};
    f32x4 accO[8];
    #pragma unroll
    for (int i = 0; i < 8; ++i) accO[i] = (f32x4){0.f, 0.f, 0.f, 0.f};

    const int kwave0 = wave * 512;
    const size_t browbase = (size_t)b * LSEQ;

    for (int it = 0; it < 16; ++it) {
        const int kb = kwave0 + it * 32;
        f32x4 s0 = (f32x4){0.f, 0.f, 0.f, 0.f};
        f32x4 s1 = (f32x4){0.f, 0.f, 0.f, 0.f};
        {
            const float* kp0 = kg + (browbase + kb + li) * DIM + g * 8;
            const float* kp1 = kp0 + (size_t)16 * DIM;
            #pragma unroll
            for (int d = 0; d < 4; ++d) {
                const float4* a4 = reinterpret_cast<const float4*>(kp0 + d * 32);
                const float4* b4 = reinterpret_cast<const float4*>(kp1 + d * 32);
                s0 = __builtin_amdgcn_mfma_f32_16x16x32_bf16(qf[d], cvt8(a4[0], a4[1]), s0, 0, 0, 0);
                s1 = __builtin_amdgcn_mfma_f32_16x16x32_bf16(qf[d], cvt8(b4[0], b4[1]), s1, 0, 0, 0);
            }
        }
        const int* mbase = maskg + (browbase + q0) * LSEQ + kb + li;
        #pragma unroll
        for (int t = 0; t < 2; ++t) {
            f32x4 sv = t ? s1 : s0;
            const int col = kb + t * 16 + li;
            #pragma unroll
            for (int r = 0; r < 4; ++r) {
                const int m = mbase[(size_t)(g * 4 + r) * LSEQ + t * 16];
                float sc = m ? -1.0e9f : sv[r];
                float ev = __builtin_amdgcn_exp2f(sc);
                rsum[r] += ev;
                Es[(g * 4 + r) * EPITCH + col] = (__bf16)ev;
            }
        }
        bf16x8 af = *reinterpret_cast<const bf16x8*>(&Es[li * EPITCH + kb + g * 8]);
        const float* vb = vg + (browbase + kb + g * 8) * DIM + li;
        #pragma unroll
        for (int dt = 0; dt < 8; ++dt) {
            const float* vp = vb + dt * 16;
            bf16x8 bf;
            #pragma unroll
            for (int j = 0; j < 8; ++j) bf[j] = (__bf16)vp[(size_t)j * DIM];
            accO[dt] = __builtin_amdgcn_mfma_f32_16x16x32_bf16(af, bf, accO[dt], 0, 0, 0);
        }
    }

    #pragma unroll
    for (int off = 1; off < 16; off <<= 1) {
        #pragma unroll
        for (int r = 0; r < 4; ++r) rsum[r] += __shfl_xor(rsum[r], off, 64);
    }
    if (li == 0) {
        #pragma unroll
        for (int r = 0; r < 4; ++r) rowpart[wave][g * 4 + r] = rsum[r];
    }
    __syncthreads();
    #pragma unroll
    for (int dt = 0; dt < 8; ++dt) {
        #pragma unroll
        for (int r = 0; r < 4; ++r)
            atomicAdd(&Osum[(g * 4 + r) * DIM + dt * 16 + li], accO[dt][r]);
    }
    if (tid < 16) {
        float s = rowpart[0][tid] + rowpart[1][tid] + rowpart[2][tid] + rowpart[3][tid];
        rowinv[tid] = 1.0f / s;
    }
    __syncthreads();

    const size_t wbase = (browbase + q0) * LSEQ;
    for (int i = tid; i < 16 * (LSEQ / 8); i += 256) {
        const int row = i >> 8;
        const int col = (i & 255) * 8;
        bf16x8 e = *reinterpret_cast<const bf16x8*>(&Es[row * EPITCH + col]);
        const float inv = rowinv[row];
        float4 w0, w1;
        w0.x = (float)e[0] * inv; w0.y = (float)e[1] * inv;
        w0.z = (float)e[2] * inv; w0.w = (float)e[3] * inv;
        w1.x = (float)e[4] * inv; w1.y = (float)e[5] * inv;
        w1.z = (float)e[6] * inv; w1.w = (float)e[7] * inv;
        float* dst = wg + wbase + (size_t)row * LSEQ + col;
        *reinterpret_cast<float4*>(dst)     = w0;
        *reinterpret_cast<float4*>(dst + 4) = w1;
    }
    const size_t obase = (browbase + q0) * DIM;
    for (int i = tid; i < 16 * DIM; i += 256) {
        const int row = i >> 7;
        og[obase + i] = Osum[i] * rowinv[row];
    }
}

extern "C" void kernel_launch(void* const* d_in, const int* in_sizes, int n_in,
                              void* d_out, int out_size, void* d_ws, size_t ws_size,
                              hipStream_t stream) {
    const float* q    = (const float*)d_in[0];
    const float* k    = (const float*)d_in[1];
    const float* v    = (const float*)d_in[2];
    const int*   mask = (const int*)d_in[3];
    float* o = (float*)d_out;
    float* w = (float*)d_out + (size_t)BATCH * LSEQ * DIM;

    const size_t kfSize = (size_t)BATCH * NKBLK * 8 * 64 * sizeof(bf16x8);   // 8.4 MB
    const size_t vfSize = kfSize;                                            // 8.4 MB
    const size_t need   = kfSize + vfSize;                                   // 16.8 MB

    if (ws_size >= need) {
        bf16x8* kfp = (bf16x8*)d_ws;
        bf16x8* vfp = (bf16x8*)((char*)d_ws + kfSize);
        pack_k_kernel<<<dim3(NKBLK, BATCH), 256, 0, stream>>>(k, kfp);
        pack_v_kernel<<<dim3(NKBLK, BATCH), 256, 0, stream>>>(v, vfp);
        attn_fused<<<512, 512, 0, stream>>>(q, kfp, vfp, mask, o, w);
    } else {
        dim3 grid(LSEQ / 16, BATCH);
        sdpa_fused_plain<<<grid, 256, 0, stream>>>(q, k, v, mask, o, w);
    }
}

// Round 21
// 176.954 us; speedup vs baseline: 1.3656x; 1.3656x over previous
//
#include <hip/hip_runtime.h>
#include <hip/hip_bf16.h>

typedef __attribute__((ext_vector_type(8))) __bf16 bf16x8;
typedef __attribute__((ext_vector_type(4))) float f32x4;

#define BATCH 16
#define LSEQ 2048
#define DIM 128
#define EPITCH 2056
#define NKBLK 64   // 2048 / 32

__device__ __forceinline__ bf16x8 cvt8(float4 a, float4 b) {
    bf16x8 r;
    r[0] = (__bf16)a.x; r[1] = (__bf16)a.y; r[2] = (__bf16)a.z; r[3] = (__bf16)a.w;
    r[4] = (__bf16)b.x; r[5] = (__bf16)b.y; r[6] = (__bf16)b.z; r[7] = (__bf16)b.w;
    return r;
}

// ============ preproc: K -> fragment-blocked Kf[b][kblk][j][lane] ============
__global__ __launch_bounds__(256)
void pack_k_kernel(const float* __restrict__ kg, bf16x8* __restrict__ kf) {
    __shared__ __bf16 Ks[32][DIM + 8];
    const int kblk = blockIdx.x, b = blockIdx.y;
    const int tid = threadIdx.x;
    {
        const int r = tid >> 3, c4 = tid & 7;
        const float* src = kg + ((size_t)b * LSEQ + kblk * 32 + r) * DIM;
        #pragma unroll
        for (int jj = 0; jj < 4; ++jj) {
            const int c = (c4 + 8 * jj) * 4;
            float4 x = *reinterpret_cast<const float4*>(src + c);
            Ks[r][c + 0] = (__bf16)x.x; Ks[r][c + 1] = (__bf16)x.y;
            Ks[r][c + 2] = (__bf16)x.z; Ks[r][c + 3] = (__bf16)x.w;
        }
    }
    __syncthreads();
    const int lane = tid & 63, w = tid >> 6;
    const int g = lane >> 4, li = lane & 15;
    bf16x8* dst = kf + ((size_t)b * NKBLK + kblk) * 8 * 64;
    #pragma unroll
    for (int jj = 0; jj < 2; ++jj) {
        const int j = 2 * w + jj;
        const int t = j >> 2, d = j & 3;
        bf16x8 v;
        #pragma unroll
        for (int e = 0; e < 8; ++e) v[e] = Ks[t * 16 + li][d * 32 + g * 8 + e];
        dst[j * 64 + lane] = v;
    }
}

// ============ preproc: V -> fragment-blocked Vf[b][kblk][dt][lane] ============
__global__ __launch_bounds__(256)
void pack_v_kernel(const float* __restrict__ vg, bf16x8* __restrict__ vf) {
    __shared__ __bf16 Vs[32][DIM + 8];
    const int kblk = blockIdx.x, b = blockIdx.y;
    const int tid = threadIdx.x;
    {
        const int r = tid >> 3, c4 = tid & 7;
        const float* src = vg + ((size_t)b * LSEQ + kblk * 32 + r) * DIM;
        #pragma unroll
        for (int jj = 0; jj < 4; ++jj) {
            const int c = (c4 + 8 * jj) * 4;
            float4 x = *reinterpret_cast<const float4*>(src + c);
            Vs[r][c + 0] = (__bf16)x.x; Vs[r][c + 1] = (__bf16)x.y;
            Vs[r][c + 2] = (__bf16)x.z; Vs[r][c + 3] = (__bf16)x.w;
        }
    }
    __syncthreads();
    const int lane = tid & 63, w = tid >> 6;
    const int g = lane >> 4, li = lane & 15;
    bf16x8* dst = vf + ((size_t)b * NKBLK + kblk) * 8 * 64;
    #pragma unroll
    for (int jj = 0; jj < 2; ++jj) {
        const int dt = 2 * w + jj;
        bf16x8 v;
        #pragma unroll
        for (int e = 0; e < 8; ++e) v[e] = Vs[g * 8 + e][dt * 16 + li];
        dst[dt * 64 + lane] = v;
    }
}

// ============ attn_fused: 2-pass, no E buffer, full-line W stores ============
__global__ __launch_bounds__(256, 2)
void attn_fused(const float* __restrict__ qg,
                const bf16x8* __restrict__ kf,
                const bf16x8* __restrict__ vf,
                const int* __restrict__ maskg,
                float* __restrict__ og,
                float* __restrict__ wg)
{
    __shared__ bf16x8 Kst[512];                        // 8 KB
    __shared__ bf16x8 Vst[512];                        // 8 KB
    __shared__ __align__(16) __bf16 P[4][16][40];      // 5.1 KB
    __shared__ unsigned char MB[4][NKBLK][64];         // 16 KB mask bytes for pass 2
    __shared__ __align__(16) float Wst[4][16][36];     // 9 KB W staging (pass 2)

    const int tid  = threadIdx.x;
    const int wave = tid >> 6;     // 0..3
    const int lane = tid & 63;
    const int g    = lane >> 4;
    const int li   = lane & 15;

    // XCD pinning: batch b -> xcd b%8
    const int wgid = blockIdx.x;           // 0..511
    const int xcd  = wgid & 7;
    const int rest = wgid >> 3;            // 0..63
    const int b    = xcd + 8 * (rest & 1);
    const int qb   = rest >> 1;            // 0..31 (64-query block)
    const int q0   = qb * 64 + wave * 16;  // this wave's 16 queries

    const size_t bb = (size_t)b * LSEQ;

    // Q fragments with scale*log2(e)
    const float qscale = 0.08838834764831845f * 1.4426950408889634f;
    bf16x8 qf[4];
    {
        const float* qrow = qg + (bb + q0 + li) * DIM + g * 8;
        #pragma unroll
        for (int d = 0; d < 4; ++d) {
            const float4* p4 = reinterpret_cast<const float4*>(qrow + d * 32);
            float4 x = p4[0];
            float4 y = p4[1];
            x.x *= qscale; x.y *= qscale; x.z *= qscale; x.w *= qscale;
            y.x *= qscale; y.y *= qscale; y.z *= qscale; y.w *= qscale;
            qf[d] = cvt8(x, y);
        }
    }

    float rsum[4] = {0.f, 0.f, 0.f, 0.f};
    f32x4 accO[8];
    #pragma unroll
    for (int i = 0; i < 8; ++i) accO[i] = (f32x4){0.f, 0.f, 0.f, 0.f};

    const bf16x8* KbU = kf + (size_t)b * NKBLK * 512;
    const bf16x8* VbU = vf + (size_t)b * NKBLK * 512;
    // mask in fragment order: element (t2,r) at iter t = mpQ[r*LSEQ + t*32 + t2*16]
    const int* mpQ = maskg + (bb + q0 + g * 4) * (size_t)LSEQ + li;

    // ================= PASS 1: rowsum + PV + O =================
    bf16x8 ka = KbU[tid], kb2 = KbU[256 + tid];
    bf16x8 va = VbU[tid], vb2 = VbU[256 + tid];
    int mcur[8], mnxt[8];
    #pragma unroll
    for (int j = 0; j < 8; ++j) {
        const int t2 = j >> 2, r = j & 3;
        mcur[j] = mpQ[(size_t)r * LSEQ + t2 * 16];
    }

    for (int t = 0; t < NKBLK; ++t) {
        Kst[tid] = ka; Kst[256 + tid] = kb2;
        Vst[tid] = va; Vst[256 + tid] = vb2;
        __syncthreads();

        bf16x8 kc[8], vc[8];
        #pragma unroll
        for (int j = 0; j < 8; ++j) kc[j] = Kst[j * 64 + lane];
        #pragma unroll
        for (int j = 0; j < 8; ++j) vc[j] = Vst[j * 64 + lane];

        // prefetch tile t+1 (K, V, mask)
        if (t + 1 < NKBLK) {
            const size_t un = (size_t)(t + 1) * 512;
            ka = KbU[un + tid];  kb2 = KbU[un + 256 + tid];
            va = VbU[un + tid];  vb2 = VbU[un + 256 + tid];
            #pragma unroll
            for (int j = 0; j < 8; ++j) {
                const int t2 = j >> 2, r = j & 3;
                mnxt[j] = mpQ[(size_t)r * LSEQ + (t + 1) * 32 + t2 * 16];
            }
        }
        __syncthreads();

        // QK^T
        f32x4 s0 = (f32x4){0.f, 0.f, 0.f, 0.f};
        f32x4 s1 = (f32x4){0.f, 0.f, 0.f, 0.f};
        #pragma unroll
        for (int d = 0; d < 4; ++d) {
            s0 = __builtin_amdgcn_mfma_f32_16x16x32_bf16(qf[d], kc[d],     s0, 0, 0, 0);
            s1 = __builtin_amdgcn_mfma_f32_16x16x32_bf16(qf[d], kc[4 + d], s1, 0, 0, 0);
        }

        // mask + exp2 + P stage + rowsum; pack byte for pass 2
        unsigned byte = 0;
        #pragma unroll
        for (int t2 = 0; t2 < 2; ++t2) {
            f32x4 sv = t2 ? s1 : s0;
            #pragma unroll
            for (int r = 0; r < 4; ++r) {
                const int j = t2 * 4 + r;
                const bool msk = (mcur[j] != 0);
                byte |= (msk ? 1u : 0u) << j;
                float sc = msk ? -1.0e9f : sv[r];
                float ev = __builtin_amdgcn_exp2f(sc);
                rsum[r] += ev;
                P[wave][g * 4 + r][t2 * 16 + li] = (__bf16)ev;
            }
        }
        MB[wave][t][lane] = (unsigned char)byte;

        // PV
        {
            bf16x8 af = *reinterpret_cast<const bf16x8*>(&P[wave][li][g * 8]);
            #pragma unroll
            for (int dt = 0; dt < 8; ++dt)
                accO[dt] = __builtin_amdgcn_mfma_f32_16x16x32_bf16(af, vc[dt], accO[dt], 0, 0, 0);
        }

        #pragma unroll
        for (int j = 0; j < 8; ++j) mcur[j] = mnxt[j];
    }

    // per-wave rowsum reduce across li lanes
    #pragma unroll
    for (int off = 1; off < 16; off <<= 1) {
        #pragma unroll
        for (int r = 0; r < 4; ++r) rsum[r] += __shfl_xor(rsum[r], off, 64);
    }
    float rinv[4];
    #pragma unroll
    for (int r = 0; r < 4; ++r) rinv[r] = 1.0f / rsum[r];

    // O write (nt)
    {
        float* ob = og + (bb + q0) * DIM;
        #pragma unroll
        for (int dt = 0; dt < 8; ++dt)
            #pragma unroll
            for (int r = 0; r < 4; ++r)
                __builtin_nontemporal_store(accO[dt][r] * rinv[r],
                    ob + (size_t)(g * 4 + r) * DIM + dt * 16 + li);
    }

    // ================= PASS 2: recompute QK^T, write W full-line =================
    ka = KbU[tid]; kb2 = KbU[256 + tid];
    float* wrow = wg + (bb + q0) * (size_t)LSEQ;

    for (int t = 0; t < NKBLK; ++t) {
        Kst[tid] = ka; Kst[256 + tid] = kb2;
        __syncthreads();

        bf16x8 kc[8];
        #pragma unroll
        for (int j = 0; j < 8; ++j) kc[j] = Kst[j * 64 + lane];
        const unsigned byte = MB[wave][t][lane];

        if (t + 1 < NKBLK) {
            const size_t un = (size_t)(t + 1) * 512;
            ka = KbU[un + tid];  kb2 = KbU[un + 256 + tid];
        }
        __syncthreads();

        f32x4 s0 = (f32x4){0.f, 0.f, 0.f, 0.f};
        f32x4 s1 = (f32x4){0.f, 0.f, 0.f, 0.f};
        #pragma unroll
        for (int d = 0; d < 4; ++d) {
            s0 = __builtin_amdgcn_mfma_f32_16x16x32_bf16(qf[d], kc[d],     s0, 0, 0, 0);
            s1 = __builtin_amdgcn_mfma_f32_16x16x32_bf16(qf[d], kc[4 + d], s1, 0, 0, 0);
        }

        // stage W tile in LDS (per-wave, same-wave in-order LDS: no barrier)
        #pragma unroll
        for (int t2 = 0; t2 < 2; ++t2) {
            f32x4 sv = t2 ? s1 : s0;
            #pragma unroll
            for (int r = 0; r < 4; ++r) {
                float sc = ((byte >> (t2 * 4 + r)) & 1u) ? -1.0e9f : sv[r];
                Wst[wave][g * 4 + r][t2 * 16 + li] =
                    __builtin_amdgcn_exp2f(sc) * rinv[r];
            }
        }

        // full-line W write: 8 lanes x 16B = one contiguous 128B line per row,
        // 8 rows per instruction, 2 instructions
        #pragma unroll
        for (int p = 0; p < 2; ++p) {
            const int row = p * 8 + (lane >> 3);
            const int col = (lane & 7) * 4;
            f32x4 wv = *reinterpret_cast<const f32x4*>(&Wst[wave][row][col]);
            __builtin_nontemporal_store(wv,
                reinterpret_cast<f32x4*>(wrow + (size_t)row * LSEQ + t * 32 + col));
        }
    }
}

// ========================= fallback (no workspace) =========================
__global__ __launch_bounds__(256, 2)
void sdpa_fused_plain(const float* __restrict__ qg,
                      const float* __restrict__ kg,
                      const float* __restrict__ vg,
                      const int*   __restrict__ maskg,
                      float* __restrict__ og,
                      float* __restrict__ wg)
{
    __shared__ __align__(16) __bf16 Es[16 * EPITCH];
    __shared__ float Osum[16 * DIM];
    __shared__ float rowpart[4][16];
    __shared__ float rowinv[16];

    const int tid  = threadIdx.x;
    const int wave = tid >> 6;
    const int lane = tid & 63;
    const int g    = lane >> 4;
    const int li   = lane & 15;
    const int qt = blockIdx.x;
    const int b  = blockIdx.y;
    const int q0 = qt * 16;

    for (int i = tid; i < 16 * DIM; i += 256) Osum[i] = 0.0f;

    const float qscale = 0.08838834764831845f * 1.4426950408889634f;
    bf16x8 qf[4];
    {
        const float* qrow = qg + ((size_t)b * LSEQ + q0 + li) * DIM + g * 8;
        #pragma unroll
        for (int d = 0; d < 4; ++d) {
            const float4* p4 = reinterpret_cast<const float4*>(qrow + d * 32);
            float4 x = p4[0];
            float4 y = p4[1];
            x.x *= qscale; x.y *= qscale; x.z *= qscale; x.w *= qscale;
            y.x *= qscale; y.y *= qscale; y.z *= qscale; y.w *= qscale;
            qf[d] = cvt8(x, y);
        }
    }

    float rsum[4] = {0.f, 0.f, 0.f, 0.f};
    f32x4 accO[8];
    #pragma unroll
    for (int i = 0; i < 8; ++i) accO[i] = (f32x4){0.f, 0.f, 0.f, 0.f};

    const int kwave0 = wave * 512;
    const size_t browbase = (size_t)b * LSEQ;

    for (int it = 0; it < 16; ++it) {
        const int kb = kwave0 + it * 32;
        f32x4 s0 = (f32x4){0.f, 0.f, 0.f, 0.f};
        f32x4 s1 = (f32x4){0.f, 0.f, 0.f, 0.f};
        {
            const float* kp0 = kg + (browbase + kb + li) * DIM + g * 8;
            const float* kp1 = kp0 + (size_t)16 * DIM;
            #pragma unroll
            for (int d = 0; d < 4; ++d) {
                const float4* a4 = reinterpret_cast<const float4*>(kp0 + d * 32);
                const float4* b4 = reinterpret_cast<const float4*>(kp1 + d * 32);
                s0 = __builtin_amdgcn_mfma_f32_16x16x32_bf16(qf[d], cvt8(a4[0], a4[1]), s0, 0, 0, 0);
                s1 = __builtin_amdgcn_mfma_f32_16x16x32_bf16(qf[d], cvt8(b4[0], b4[1]), s1, 0, 0, 0);
            }
        }
        const int* mbase = maskg + (browbase + q0) * LSEQ + kb + li;
        #pragma unroll
        for (int t = 0; t < 2; ++t) {
            f32x4 sv = t ? s1 : s0;
            const int col = kb + t * 16 + li;
            #pragma unroll
            for (int r = 0; r < 4; ++r) {
                const int m = mbase[(size_t)(g * 4 + r) * LSEQ + t * 16];
                float sc = m ? -1.0e9f : sv[r];
                float ev = __builtin_amdgcn_exp2f(sc);
                rsum[r] += ev;
                Es[(g * 4 + r) * EPITCH + col] = (__bf16)ev;
            }
        }
        bf16x8 af = *reinterpret_cast<const bf16x8*>(&Es[li * EPITCH + kb + g * 8]);
        const float* vb = vg + (browbase + kb + g * 8) * DIM + li;
        #pragma unroll
        for (int dt = 0; dt < 8; ++dt) {
            const float* vp = vb + dt * 16;
            bf16x8 bf;
            #pragma unroll
            for (int j = 0; j < 8; ++j) bf[j] = (__bf16)vp[(size_t)j * DIM];
            accO[dt] = __builtin_amdgcn_mfma_f32_16x16x32_bf16(af, bf, accO[dt], 0, 0, 0);
        }
    }

    #pragma unroll
    for (int off = 1; off < 16; off <<= 1) {
        #pragma unroll
        for (int r = 0; r < 4; ++r) rsum[r] += __shfl_xor(rsum[r], off, 64);
    }
    if (li == 0) {
        #pragma unroll
        for (int r = 0; r < 4; ++r) rowpart[wave][g * 4 + r] = rsum[r];
    }
    __syncthreads();
    #pragma unroll
    for (int dt = 0; dt < 8; ++dt) {
        #pragma unroll
        for (int r = 0; r < 4; ++r)
            atomicAdd(&Osum[(g * 4 + r) * DIM + dt * 16 + li], accO[dt][r]);
    }
    if (tid < 16) {
        float s = rowpart[0][tid] + rowpart[1][tid] + rowpart[2][tid] + rowpart[3][tid];
        rowinv[tid] = 1.0f / s;
    }
    __syncthreads();

    const size_t wbase = (browbase + q0) * LSEQ;
    for (int i = tid; i < 16 * (LSEQ / 8); i += 256) {
        const int row = i >> 8;
        const int col = (i & 255) * 8;
        bf16x8 e = *reinterpret_cast<const bf16x8*>(&Es[row * EPITCH + col]);
        const float inv = rowinv[row];
        float4 w0, w1;
        w0.x = (float)e[0] * inv; w0.y = (float)e[1] * inv;
        w0.z = (float)e[2] * inv; w0.w = (float)e[3] * inv;
        w1.x = (float)e[4] * inv; w1.y = (float)e[5] * inv;
        w1.z = (float)e[6] * inv; w1.w = (float)e[7] * inv;
        float* dst = wg + wbase + (size_t)row * LSEQ + col;
        *reinterpret_cast<float4*>(dst)     = w0;
        *reinterpret_cast<float4*>(dst + 4) = w1;
    }
    const size_t obase = (browbase + q0) * DIM;
    for (int i = tid; i < 16 * DIM; i += 256) {
        const int row = i >> 7;
        og[obase + i] = Osum[i] * rowinv[row];
    }
}

extern "C" void kernel_launch(void* const* d_in, const int* in_sizes, int n_in,
                              void* d_out, int out_size, void* d_ws, size_t ws_size,
                              hipStream_t stream) {
    const float* q    = (const float*)d_in[0];
    const float* k    = (const float*)d_in[1];
    const float* v    = (const float*)d_in[2];
    const int*   mask = (const int*)d_in[3];
    float* o = (float*)d_out;
    float* w = (float*)d_out + (size_t)BATCH * LSEQ * DIM;

    const size_t kfSize = (size_t)BATCH * NKBLK * 8 * 64 * sizeof(bf16x8);   // 8.4 MB
    const size_t vfSize = kfSize;                                            // 8.4 MB
    const size_t need   = kfSize + vfSize;                                   // 16.8 MB

    if (ws_size >= need) {
        bf16x8* kf  = (bf16x8*)d_ws;
        bf16x8* vfp = (bf16x8*)((char*)d_ws + kfSize);
        pack_k_kernel<<<dim3(NKBLK, BATCH), 256, 0, stream>>>(k, kf);
        pack_v_kernel<<<dim3(NKBLK, BATCH), 256, 0, stream>>>(v, vfp);
        attn_fused<<<512, 256, 0, stream>>>(q, kf, vfp, mask, o, w);
    } else {
        dim3 grid(LSEQ / 16, BATCH);
        sdpa_fused_plain<<<grid, 256, 0, stream>>>(q, k, v, mask, o, w);
    }
}